// Round 2
// baseline (23.741 us; speedup 1.0000x reference)
//
#include <hip/hip_runtime.h>

// SurfEval: NURBS surface evaluation (B=4, 1024x1024 grid, 4x4 basis window).
// Per block: one (b,u) row. Stage tu[j] = sum_l Nu[u,l]*ctrl[b,us-3+l,j] into
// LDS (128 x float4 = 2KB). Each thread then computes 4 CONSECUTIVE v-points
// and writes them as 3x float4 (48B, 16B-aligned) -> global_store_dwordx4.

#define OUT_U 1024
#define OUT_V 1024
#define MCTRL 128
#define NCTRL 128

__device__ __forceinline__ void fma4(float4& acc, float w, const float4& a) {
    acc.x = fmaf(w, a.x, acc.x);
    acc.y = fmaf(w, a.y, acc.y);
    acc.z = fmaf(w, a.z, acc.z);
    acc.w = fmaf(w, a.w, acc.w);
}

__global__ __launch_bounds__(256) void surf_eval_kernel(
    const float4* __restrict__ ctrl,   // (B,M,N)
    const float4* __restrict__ Nu,     // (OUT_U)
    const float4* __restrict__ Nv,     // (OUT_V)
    const int*    __restrict__ uspan,  // (OUT_U)
    const int*    __restrict__ vspan,  // (OUT_V)
    float*        __restrict__ out)    // (B,OUT_U,OUT_V,3)
{
    __shared__ float4 tu[NCTRL];

    const int bu  = blockIdx.x;        // b*1024 + u
    const int b   = bu >> 10;
    const int u   = bu & 1023;
    const int tid = threadIdx.x;

    const int   us = uspan[u];         // in [3,127]
    const float4 nu = Nu[u];

    // Stage 1: u-contraction into LDS (threads 0..127)
    if (tid < NCTRL) {
        const float4* row = ctrl + ((size_t)(b * MCTRL + (us - 3)) * NCTRL) + tid;
        float4 a0 = row[0];
        float4 a1 = row[NCTRL];
        float4 a2 = row[2 * NCTRL];
        float4 a3 = row[3 * NCTRL];
        float4 acc;
        acc.x = nu.x * a0.x; acc.y = nu.x * a0.y;
        acc.z = nu.x * a0.z; acc.w = nu.x * a0.w;
        fma4(acc, nu.y, a1);
        fma4(acc, nu.z, a2);
        fma4(acc, nu.w, a3);
        tu[tid] = acc;
    }
    __syncthreads();

    // Stage 2: 4 consecutive v-points per thread, packed float4 stores.
    const int v0 = tid << 2;
    const int4 vs4 = *(const int4*)(vspan + v0);

    float r[12];
#pragma unroll
    for (int k = 0; k < 4; ++k) {
        const int vs = (k == 0) ? vs4.x : (k == 1) ? vs4.y : (k == 2) ? vs4.z : vs4.w;
        const float4 nv = Nv[v0 + k];

        const float4 t0 = tu[vs - 3];
        const float4 t1 = tu[vs - 2];
        const float4 t2 = tu[vs - 1];
        const float4 t3 = tu[vs];

        float4 acc;
        acc.x = nv.x * t0.x; acc.y = nv.x * t0.y;
        acc.z = nv.x * t0.z; acc.w = nv.x * t0.w;
        fma4(acc, nv.y, t1);
        fma4(acc, nv.z, t2);
        fma4(acc, nv.w, t3);

        const float inv = __builtin_amdgcn_rcpf(acc.w);  // ~1ulp, plenty for 5.9e-2 threshold
        r[k * 3 + 0] = acc.x * inv;
        r[k * 3 + 1] = acc.y * inv;
        r[k * 3 + 2] = acc.z * inv;
    }

    float4* op = (float4*)(out + ((size_t)bu * OUT_V + (size_t)v0) * 3);
    op[0] = make_float4(r[0], r[1], r[2],  r[3]);
    op[1] = make_float4(r[4], r[5], r[6],  r[7]);
    op[2] = make_float4(r[8], r[9], r[10], r[11]);
}

extern "C" void kernel_launch(void* const* d_in, const int* in_sizes, int n_in,
                              void* d_out, int out_size, void* d_ws, size_t ws_size,
                              hipStream_t stream) {
    const float4* ctrl  = (const float4*)d_in[0];
    const float4* Nu    = (const float4*)d_in[1];
    const float4* Nv    = (const float4*)d_in[2];
    const int*    uspan = (const int*)d_in[3];
    const int*    vspan = (const int*)d_in[4];
    float*        out   = (float*)d_out;

    const int nblocks = 4 * OUT_U; // one block per (b,u) row
    surf_eval_kernel<<<nblocks, 256, 0, stream>>>(ctrl, Nu, Nv, uspan, vspan, out);
}

// Round 3
// 18.308 us; speedup vs baseline: 1.2968x; 1.2968x over previous
//
#include <hip/hip_runtime.h>

// SurfEval: NURBS surface evaluation (B=4, 1024x1024 grid, 4x4 basis window).
// Per block: one (b,u) row. Stage tu[j] = sum_l Nu[u,l]*ctrl[b,us-3+l,j] into
// LDS (128 x float4 = 2KB). Stage 2: each thread computes 2 PAIRS of
// consecutive v-points (v = 2*tid + 512*k). Lanes span ~16 tu entries per
// ds_read_b128 -> 2-way bank aliasing (free, m136). Stores: 3x float2 per
// pair (8B aligned). Divide via v_rcp_f32 (absmax 7.8e-3 << 5.9e-2 thr).

#define OUT_U 1024
#define OUT_V 1024
#define MCTRL 128
#define NCTRL 128

__device__ __forceinline__ void fma4(float4& acc, float w, const float4& a) {
    acc.x = fmaf(w, a.x, acc.x);
    acc.y = fmaf(w, a.y, acc.y);
    acc.z = fmaf(w, a.z, acc.z);
    acc.w = fmaf(w, a.w, acc.w);
}

__global__ __launch_bounds__(256) void surf_eval_kernel(
    const float4* __restrict__ ctrl,   // (B,M,N)
    const float4* __restrict__ Nu,     // (OUT_U)
    const float4* __restrict__ Nv,     // (OUT_V)
    const int*    __restrict__ uspan,  // (OUT_U)
    const int*    __restrict__ vspan,  // (OUT_V)
    float*        __restrict__ out)    // (B,OUT_U,OUT_V,3)
{
    __shared__ float4 tu[NCTRL];

    const int bu  = blockIdx.x;        // b*1024 + u
    const int b   = bu >> 10;
    const int u   = bu & 1023;
    const int tid = threadIdx.x;

    const int   us = uspan[u];         // in [3,127]
    const float4 nu = Nu[u];

    // Stage 1: u-contraction into LDS (threads 0..127)
    if (tid < NCTRL) {
        const float4* row = ctrl + ((size_t)(b * MCTRL + (us - 3)) * NCTRL) + tid;
        float4 a0 = row[0];
        float4 a1 = row[NCTRL];
        float4 a2 = row[2 * NCTRL];
        float4 a3 = row[3 * NCTRL];
        float4 acc;
        acc.x = nu.x * a0.x; acc.y = nu.x * a0.y;
        acc.z = nu.x * a0.z; acc.w = nu.x * a0.w;
        fma4(acc, nu.y, a1);
        fma4(acc, nu.z, a2);
        fma4(acc, nu.w, a3);
        tu[tid] = acc;
    }
    __syncthreads();

    // Stage 2: 2 pairs of consecutive v-points per thread.
    const size_t outrow = (size_t)bu * OUT_V;
#pragma unroll
    for (int k = 0; k < 2; ++k) {
        const int v0 = (tid << 1) + (k << 9);
        const int2 vs2 = *(const int2*)(vspan + v0);
        const float4 nv0 = Nv[v0];
        const float4 nv1 = Nv[v0 + 1];

        float4 p0, p1;
        {
            const float4 t0 = tu[vs2.x - 3];
            const float4 t1 = tu[vs2.x - 2];
            const float4 t2 = tu[vs2.x - 1];
            const float4 t3 = tu[vs2.x];
            p0.x = nv0.x * t0.x; p0.y = nv0.x * t0.y;
            p0.z = nv0.x * t0.z; p0.w = nv0.x * t0.w;
            fma4(p0, nv0.y, t1);
            fma4(p0, nv0.z, t2);
            fma4(p0, nv0.w, t3);
        }
        {
            const float4 t0 = tu[vs2.y - 3];
            const float4 t1 = tu[vs2.y - 2];
            const float4 t2 = tu[vs2.y - 1];
            const float4 t3 = tu[vs2.y];
            p1.x = nv1.x * t0.x; p1.y = nv1.x * t0.y;
            p1.z = nv1.x * t0.z; p1.w = nv1.x * t0.w;
            fma4(p1, nv1.y, t1);
            fma4(p1, nv1.z, t2);
            fma4(p1, nv1.w, t3);
        }

        const float i0 = __builtin_amdgcn_rcpf(p0.w);
        const float i1 = __builtin_amdgcn_rcpf(p1.w);

        float2* op = (float2*)(out + (outrow + (size_t)v0) * 3);
        op[0] = make_float2(p0.x * i0, p0.y * i0);
        op[1] = make_float2(p0.z * i0, p1.x * i1);
        op[2] = make_float2(p1.y * i1, p1.z * i1);
    }
}

extern "C" void kernel_launch(void* const* d_in, const int* in_sizes, int n_in,
                              void* d_out, int out_size, void* d_ws, size_t ws_size,
                              hipStream_t stream) {
    const float4* ctrl  = (const float4*)d_in[0];
    const float4* Nu    = (const float4*)d_in[1];
    const float4* Nv    = (const float4*)d_in[2];
    const int*    uspan = (const int*)d_in[3];
    const int*    vspan = (const int*)d_in[4];
    float*        out   = (float*)d_out;

    const int nblocks = 4 * OUT_U; // one block per (b,u) row
    surf_eval_kernel<<<nblocks, 256, 0, stream>>>(ctrl, Nu, Nv, uspan, vspan, out);
}

// Round 4
// 15.651 us; speedup vs baseline: 1.5169x; 1.1697x over previous
//
#include <hip/hip_runtime.h>

// SurfEval: NURBS surface evaluation (B=4, 1024x1024 grid, 4x4 basis window).
// Structure = R0 (fastest so far): one block per (b,u) row; tu[] staged in LDS;
// stage 2 lane mapping v = tid + 256k -> consecutive lanes read consecutive v
// -> tu reads are 8-lane broadcasts of consecutive entries (conflict-free).
// Changes vs R0:
//  - store 12B per point as ONE global_store_dwordx3 (ext_vector float3,
//    align 4) instead of 3 scalar dwords: 3x fewer write-path line requests.
//  - perspective divide via v_rcp_f32 (absmax 7.8e-3 << 5.9e-2 threshold).

#define OUT_U 1024
#define OUT_V 1024
#define MCTRL 128
#define NCTRL 128

typedef float vfloat3 __attribute__((ext_vector_type(3), aligned(4)));

__device__ __forceinline__ void fma4(float4& acc, float w, const float4& a) {
    acc.x = fmaf(w, a.x, acc.x);
    acc.y = fmaf(w, a.y, acc.y);
    acc.z = fmaf(w, a.z, acc.z);
    acc.w = fmaf(w, a.w, acc.w);
}

__global__ __launch_bounds__(256) void surf_eval_kernel(
    const float4* __restrict__ ctrl,   // (B,M,N)
    const float4* __restrict__ Nu,     // (OUT_U)
    const float4* __restrict__ Nv,     // (OUT_V)
    const int*    __restrict__ uspan,  // (OUT_U)
    const int*    __restrict__ vspan,  // (OUT_V)
    float*        __restrict__ out)    // (B,OUT_U,OUT_V,3)
{
    __shared__ float4 tu[NCTRL];

    const int bu  = blockIdx.x;        // b*1024 + u
    const int b   = bu >> 10;
    const int u   = bu & 1023;
    const int tid = threadIdx.x;

    const int   us = uspan[u];         // in [3,127]
    const float4 nu = Nu[u];

    // Stage 1: u-contraction into LDS (threads 0..127)
    if (tid < NCTRL) {
        const float4* row = ctrl + ((size_t)(b * MCTRL + (us - 3)) * NCTRL) + tid;
        float4 a0 = row[0];
        float4 a1 = row[NCTRL];
        float4 a2 = row[2 * NCTRL];
        float4 a3 = row[3 * NCTRL];
        float4 acc;
        acc.x = nu.x * a0.x; acc.y = nu.x * a0.y;
        acc.z = nu.x * a0.z; acc.w = nu.x * a0.w;
        fma4(acc, nu.y, a1);
        fma4(acc, nu.z, a2);
        fma4(acc, nu.w, a3);
        tu[tid] = acc;
    }
    __syncthreads();

    // Stage 2: 4 v-points per thread, v = tid + 256k (consecutive lanes ->
    // consecutive v). One dwordx3 store per point.
    const size_t outrow = (size_t)bu * OUT_V;
#pragma unroll
    for (int k = 0; k < 4; ++k) {
        const int v  = tid + k * 256;
        const int vs = vspan[v];       // in [3,127]
        const float4 nv = Nv[v];

        const float4 t0 = tu[vs - 3];
        const float4 t1 = tu[vs - 2];
        const float4 t2 = tu[vs - 1];
        const float4 t3 = tu[vs];

        float4 acc;
        acc.x = nv.x * t0.x; acc.y = nv.x * t0.y;
        acc.z = nv.x * t0.z; acc.w = nv.x * t0.w;
        fma4(acc, nv.y, t1);
        fma4(acc, nv.z, t2);
        fma4(acc, nv.w, t3);

        const float inv = __builtin_amdgcn_rcpf(acc.w);
        vfloat3 res;
        res.x = acc.x * inv;
        res.y = acc.y * inv;
        res.z = acc.z * inv;
        *(vfloat3*)(out + (outrow + (size_t)v) * 3) = res;
    }
}

extern "C" void kernel_launch(void* const* d_in, const int* in_sizes, int n_in,
                              void* d_out, int out_size, void* d_ws, size_t ws_size,
                              hipStream_t stream) {
    const float4* ctrl  = (const float4*)d_in[0];
    const float4* Nu    = (const float4*)d_in[1];
    const float4* Nv    = (const float4*)d_in[2];
    const int*    uspan = (const int*)d_in[3];
    const int*    vspan = (const int*)d_in[4];
    float*        out   = (float*)d_out;

    const int nblocks = 4 * OUT_U; // one block per (b,u) row
    surf_eval_kernel<<<nblocks, 256, 0, stream>>>(ctrl, Nu, Nv, uspan, vspan, out);
}